// Round 1
// 196.870 us; speedup vs baseline: 1.0060x; 1.0060x over previous
//
#include <hip/hip_runtime.h>
#include <math.h>

#define B 8
#define T 4096
#define D 512
#define NPAIR ((B * D) / 2)   // 2048 signal pairs
#define TOPK 7                // int(log(2047)) = 7
// PAD2: breaks the 272-stride bank alignment that made drev-gathers 16-way
// conflicted under e+(e>>4). Under this pad every access pattern in the
// kernel spreads 4 lanes/bank-pair (the ds_read_b64 minimum).
#define PAD(e) ((e) + ((e) >> 4) + ((e) >> 8))

// base-16 digit reverse of a 12-bit index (3 hex digits)
__device__ __forceinline__ int drev(int k) {
  return ((k & 15) << 8) | (k & 240) | (k >> 8);
}

__device__ __forceinline__ float2 cmul(float2 a, float2 b) {
  return make_float2(a.x * b.x - a.y * b.y, a.x * b.y + a.y * b.x);
}
__device__ __forceinline__ float2 cadd(float2 a, float2 b) { return make_float2(a.x + b.x, a.y + b.y); }
__device__ __forceinline__ float2 csub(float2 a, float2 b) { return make_float2(a.x - b.x, a.y - b.y); }
__device__ __forceinline__ float2 cmul_negi(float2 a) { return make_float2(a.y, -a.x); }  // a * (-i)

// forward 4-pt DFT, natural order, in place
__device__ __forceinline__ void dft4(float2& a, float2& b, float2& c, float2& d) {
  const float2 t0 = cadd(a, c), t1 = csub(a, c);
  const float2 t2 = cadd(b, d), t3n = cmul_negi(csub(b, d));   // -i*(b-d)
  a = cadd(t0, t2);
  b = cadd(t1, t3n);
  c = csub(t0, t2);
  d = csub(t1, t3n);
}

// forward 16-pt DFT in registers. Input natural order r[n].
// Output: X16[k] lands in r[SW4(k)], SW4(k) = ((k&3)<<2)|(k>>2).
#define C16 0.92387953251f
#define S16 0.38268343236f
#define RS2 0.70710678119f
__device__ __forceinline__ void dft16(float2 r[16]) {
  dft4(r[0], r[4], r[8],  r[12]);
  dft4(r[1], r[5], r[9],  r[13]);
  dft4(r[2], r[6], r[10], r[14]);
  dft4(r[3], r[7], r[11], r[15]);
  const float2 W1 = make_float2(C16, -S16);
  const float2 W2 = make_float2(RS2, -RS2);
  const float2 W3 = make_float2(S16, -C16);
  const float2 W6 = make_float2(-RS2, -RS2);
  const float2 W9 = make_float2(-C16, S16);
  r[5]  = cmul(r[5],  W1);
  r[9]  = cmul(r[9],  W2);
  r[13] = cmul(r[13], W3);
  r[6]  = cmul(r[6],  W2);
  r[10] = cmul_negi(r[10]);        // W16^4 = -i
  r[14] = cmul(r[14], W6);
  r[7]  = cmul(r[7],  W3);
  r[11] = cmul(r[11], W6);
  r[15] = cmul(r[15], W9);
  dft4(r[0],  r[1],  r[2],  r[3]);
  dft4(r[4],  r[5],  r[6],  r[7]);
  dft4(r[8],  r[9],  r[10], r[11]);
  dft4(r[12], r[13], r[14], r[15]);
}
#define SW4(k) ((((k) & 3) << 2) | ((k) >> 2))

// ---------------------------------------------------------------------------
// Kernel 1: transpose + pack. x (B,T,D) f32 -> xp (B, D/2, T) float2  (unchanged)
// ---------------------------------------------------------------------------
__global__ __launch_bounds__(256) void k_transpose_pack(const float* __restrict__ x,
                                                        float2* __restrict__ xp) {
  __shared__ float tT[64][65];     // [d][t]
  const int b  = blockIdx.z;
  const int t0 = blockIdx.x * 64;
  const int d0 = blockIdx.y * 64;
  const int tid = threadIdx.x;

  const int c4 = tid & 15;
  const int r0 = tid >> 4;
  for (int r = r0; r < 64; r += 16) {
    const float4 v = *(const float4*)&x[((size_t)b * T + (t0 + r)) * D + d0 + 4 * c4];
    tT[4 * c4 + 0][r] = v.x;
    tT[4 * c4 + 1][r] = v.y;
    tT[4 * c4 + 2][r] = v.z;
    tT[4 * c4 + 3][r] = v.w;
  }
  __syncthreads();

  const int tt  = tid & 31;
  const int rp0 = tid >> 5;
  for (int rp = rp0; rp < 32; rp += 8) {
    const float2 a  = *(const float2*)&tT[2 * rp][2 * tt];
    const float2 bb = *(const float2*)&tT[2 * rp + 1][2 * tt];
    const float4 o = make_float4(a.x, bb.x, a.y, bb.y);
    *(float4*)&xp[((size_t)b * (D / 2) + (d0 / 2 + rp)) * T + t0 + 2 * tt] = o;
  }
}

// ---------------------------------------------------------------------------
// Kernel 2: register-resident 16x16x16 forward FFT (2 LDS exchanges),
// spectrum stored base-16 digit-reversed in LDS, then top-7 per real signal.
// Top-k restructured: per-wave barrier-free top-7 (both shelves' shuffle
// chains interleaved), single barrier, then waves 0/1 merge 28 candidates
// per shelf and write coefficients directly to global. 18 barriers -> 4.
// ---------------------------------------------------------------------------
__global__ __launch_bounds__(256) void k_fft_topk(float2* __restrict__ xp) {
  __shared__ float2 Z[PAD(T - 1) + 1];   // 4366 float2 ~ 34.9 KB
  __shared__ float  s_cv[2][4][8];       // per-shelf, per-wave top-7 values
  __shared__ int    s_ck[2][4][8];       // per-shelf, per-wave top-7 bins

  const int tid  = threadIdx.x;
  const int lane = tid & 63;
  const int wid  = tid >> 6;
  float2* g = xp + (size_t)blockIdx.x * T;

  float2 r[16];
  // coalesced stride-256 loads straight into registers
  #pragma unroll
  for (int a = 0; a < 16; ++a) r[a] = g[(a << 8) + tid];

  // ---- stage A: DFT over high digit; twiddle W4096^(m*k1); scatter k1-major
  dft16(r);
  {
    float s, c;
    __sincosf(6.283185307179586f / 4096.0f * (float)tid, &s, &c);
    const float2 w = make_float2(c, -s);
    float2 t = make_float2(1.0f, 0.0f);
    Z[PAD(tid)] = r[0];
    #pragma unroll
    for (int k1 = 1; k1 < 16; ++k1) {
      t = cmul(t, w);
      Z[PAD((k1 << 8) + tid)] = cmul(r[SW4(k1)], t);
    }
  }
  __syncthreads();

  // ---- stage B: thread (k1, m1) = (tid>>4, tid&15); DFT over mid digit
  {
    const int m1 = tid & 15;
    const int base = ((tid >> 4) << 8) + m1;
    #pragma unroll
    for (int m2 = 0; m2 < 16; ++m2) r[m2] = Z[PAD(base + (m2 << 4))];
    dft16(r);
    float s, c;
    __sincosf(6.283185307179586f / 256.0f * (float)m1, &s, &c);
    const float2 w = make_float2(c, -s);
    float2 t = make_float2(1.0f, 0.0f);
    Z[PAD(base)] = r[0];                 // read-set == write-set: no barrier
    #pragma unroll
    for (int p = 1; p < 16; ++p) {
      t = cmul(t, w);
      Z[PAD(base + (p << 4))] = cmul(r[SW4(p)], t);
    }
  }
  __syncthreads();

  // ---- stage C: thread (k1, p); DFT over low digit; X[256q+16p+k1] -> e=base+q
  {
    const int base = tid << 4;
    #pragma unroll
    for (int m1 = 0; m1 < 16; ++m1) r[m1] = Z[PAD(base + m1)];
    dft16(r);
    #pragma unroll
    for (int q = 0; q < 16; ++q) Z[PAD(base + q)] = r[SW4(q)];
  }
  __syncthreads();

  // ---- register-resident squared amplitudes, bins k = 1+tid+256j
  float a1v[8], a2v[8];
  #pragma unroll
  for (int j = 0; j < 8; ++j) {
    const int k = 1 + tid + (j << 8);
    if (k >= T / 2) { a1v[j] = -1e30f; a2v[j] = -1e30f; continue; }
    const float2 zk = Z[PAD(drev(k))];
    const float2 zn = Z[PAD(drev(T - k))];
    const float x1r = 0.5f * (zk.x + zn.x), x1i = 0.5f * (zk.y - zn.y);
    const float x2r = 0.5f * (zk.y + zn.y), x2i = 0.5f * (zn.x - zk.x);
    a1v[j] = x1r * x1r + x1i * x1i;
    a2v[j] = x2r * x2r + x2i * x2i;
  }

  // ---- per-wave top-7, both shelves interleaved, NO barriers.
  // Global top-7 is a subset of the union of per-wave top-7s; lowest-k
  // tie-break is preserved by the two-level reduction.
  #pragma unroll
  for (int it = 0; it < TOPK; ++it) {
    // local scan of 8 bins, both shelves
    float bv0 = -1e30f, bv1 = -1e30f;
    int bj0 = 0, bj1 = 0;
    #pragma unroll
    for (int j = 0; j < 8; ++j) {
      if (a1v[j] > bv0) { bv0 = a1v[j]; bj0 = j; }
      if (a2v[j] > bv1) { bv1 = a2v[j]; bj1 = j; }
    }
    int bk0 = 1 + tid + (bj0 << 8);
    int bk1 = 1 + tid + (bj1 << 8);
    // two independent butterfly chains interleaved (hides DS latency)
    #pragma unroll
    for (int off = 1; off < 64; off <<= 1) {
      const float ov0 = __shfl_xor(bv0, off);
      const int   ok0 = __shfl_xor(bk0, off);
      const float ov1 = __shfl_xor(bv1, off);
      const int   ok1 = __shfl_xor(bk1, off);
      if (ov0 > bv0 || (ov0 == bv0 && ok0 < bk0)) { bv0 = ov0; bk0 = ok0; }
      if (ov1 > bv1 || (ov1 == bv1 && ok1 < bk1)) { bv1 = ov1; bk1 = ok1; }
    }
    if (lane == 0) {
      s_cv[0][wid][it] = bv0; s_ck[0][wid][it] = bk0;
      s_cv[1][wid][it] = bv1; s_ck[1][wid][it] = bk1;
    }
    // owning thread clears the winning bin (static-index predicated loop)
    if (((bk0 - 1) & 255) == tid) {
      const int j = (bk0 - 1) >> 8;
      #pragma unroll
      for (int jj = 0; jj < 8; ++jj) if (jj == j) a1v[jj] = -1e30f;
    }
    if (((bk1 - 1) & 255) == tid) {
      const int j = (bk1 - 1) >> 8;
      #pragma unroll
      for (int jj = 0; jj < 8; ++jj) if (jj == j) a2v[jj] = -1e30f;
    }
  }
  __syncthreads();

  // ---- merge: wave 0 handles shelf 0, wave 1 handles shelf 1, concurrently.
  // 28 real candidates padded to 32; upper half-wave duplicates them
  // (harmless for the butterfly). Winner lane writes coeff straight to global.
  if (wid < 2) {
    const int sh = wid;
    const int w  = (lane >> 3) & 3;
    const int i  = lane & 7;
    float cv = (i < TOPK) ? s_cv[sh][w][i] : -1e30f;
    int   ck = (i < TOPK) ? s_ck[sh][w][i] : 0x7fffffff;
    float4* cf = (float4*)g;
    #pragma unroll
    for (int it = 0; it < TOPK; ++it) {
      float bv = cv; int bk = ck;
      #pragma unroll
      for (int off = 1; off < 64; off <<= 1) {
        const float ov = __shfl_xor(bv, off);
        const int   ok = __shfl_xor(bk, off);
        if (ov > bv || (ov == bv && ok < bk)) { bv = ov; bk = ok; }
      }
      if (lane == it) {
        const float2 zk = Z[PAD(drev(bk))];
        const float2 zn = Z[PAD(drev(T - bk))];
        float re, im;
        if (sh == 0) { re = 0.5f * (zk.x + zn.x); im = 0.5f * (zk.y - zn.y); }
        else         { re = 0.5f * (zk.y + zn.y); im = 0.5f * (zn.x - zk.x); }
        cf[sh * TOPK + it] = make_float4((float)bk, re, im, 0.0f);
      }
      if (ck == bk) cv = -1e30f;   // candidate k's are unique; clears both copies
    }
  }
}

// ---------------------------------------------------------------------------
// Kernel 3: direct sparse reconstruction, 64t x 64d tile per block (unchanged)
// ---------------------------------------------------------------------------
__global__ __launch_bounds__(256) void k_eval(const float* __restrict__ ws,
                                              float* __restrict__ out) {
  __shared__ float  tile[64][64];
  __shared__ float4 s_coef[64 * TOPK];

  const int tid = threadIdx.x;
  const int b   = blockIdx.z;
  const int d0  = blockIdx.y * 64;
  const int t0  = blockIdx.x * 64;

  for (int idx = tid; idx < 64 * TOPK; idx += 256) {
    const int s = idx / TOPK, j = idx - s * TOPK;
    const int P = (b * D + d0) / 2 + (s >> 1);
    const int sh = s & 1;
    s_coef[idx] = ((const float4*)(ws + (size_t)P * (2 * T)))[sh * TOPK + j];
  }
  __syncthreads();

  const int dl = tid & 63;
  const int tg = tid >> 6;
  const float w0 = 6.283185307179586f / 4096.0f;

  float re[TOPK], im[TOPK], cc[TOPK], ss[TOPK], cd[TOPK], sd[TOPK];
  const int ts = t0 + tg;
  #pragma unroll
  for (int j = 0; j < TOPK; ++j) {
    const float4 v = s_coef[dl * TOPK + j];
    const int k = (int)v.x;
    re[j] = 2.0f * v.y;
    im[j] = 2.0f * v.z;
    const float a0 = w0 * (float)((k * ts) & (T - 1));
    const float ad = w0 * (float)((4 * k) & (T - 1));
    ss[j] = __sinf(a0); cc[j] = __cosf(a0);
    sd[j] = __sinf(ad); cd[j] = __cosf(ad);
  }

  #pragma unroll
  for (int i = 0; i < 16; ++i) {
    float acc = 0.0f;
    #pragma unroll
    for (int j = 0; j < TOPK; ++j) {
      acc += re[j] * cc[j] - im[j] * ss[j];
      const float nc = cc[j] * cd[j] - ss[j] * sd[j];
      const float ns = ss[j] * cd[j] + cc[j] * sd[j];
      cc[j] = nc; ss[j] = ns;
    }
    tile[tg + 4 * i][dl] = acc;
  }
  __syncthreads();

  const int c4 = tid & 15;
  const int rw = tid >> 4;
  for (int rr = rw; rr < 64; rr += 16) {
    const float4 v = *(const float4*)&tile[rr][4 * c4];
    *(float4*)&out[((size_t)b * T + (t0 + rr)) * D + d0 + 4 * c4] = v;
  }
}

// ---------------------------------------------------------------------------
extern "C" void kernel_launch(void* const* d_in, const int* in_sizes, int n_in,
                              void* d_out, int out_size, void* d_ws, size_t ws_size,
                              hipStream_t stream) {
  const float* x = (const float*)d_in[0];
  float* out = (float*)d_out;
  float2* xp = (float2*)d_ws;

  dim3 tgrid(T / 64, D / 64, B);
  hipLaunchKernelGGL(k_transpose_pack, tgrid, dim3(256), 0, stream, x, xp);
  hipLaunchKernelGGL(k_fft_topk, dim3(NPAIR), dim3(256), 0, stream, xp);
  hipLaunchKernelGGL(k_eval, tgrid, dim3(256), 0, stream, (const float*)d_ws, out);
}

// Round 3
// 175.665 us; speedup vs baseline: 1.1274x; 1.1207x over previous
//
#include <hip/hip_runtime.h>
#include <math.h>

#define B 8
#define T 4096
#define D 512
#define NPAIR ((B * D) / 2)   // 2048 signal pairs
#define TOPK 7                // int(log(2047)) = 7
// PAD2: breaks the 272-stride bank alignment that made drev-gathers 16-way
// conflicted under e+(e>>4).
#define PAD(e) ((e) + ((e) >> 4) + ((e) >> 8))

// base-16 digit reverse of a 12-bit index (3 hex digits)
__device__ __forceinline__ int drev(int k) {
  return ((k & 15) << 8) | (k & 240) | (k >> 8);
}

__device__ __forceinline__ float2 cmul(float2 a, float2 b) {
  return make_float2(a.x * b.x - a.y * b.y, a.x * b.y + a.y * b.x);
}
__device__ __forceinline__ float2 cadd(float2 a, float2 b) { return make_float2(a.x + b.x, a.y + b.y); }
__device__ __forceinline__ float2 csub(float2 a, float2 b) { return make_float2(a.x - b.x, a.y - b.y); }
__device__ __forceinline__ float2 cmul_negi(float2 a) { return make_float2(a.y, -a.x); }  // a * (-i)

__device__ __forceinline__ unsigned long long shfl_xor_u64(unsigned long long v, int off) {
  const unsigned lo = __shfl_xor((unsigned)v, off);
  const unsigned hi = __shfl_xor((unsigned)(v >> 32), off);
  return ((unsigned long long)hi << 32) | lo;
}

// forward 4-pt DFT, natural order, in place
__device__ __forceinline__ void dft4(float2& a, float2& b, float2& c, float2& d) {
  const float2 t0 = cadd(a, c), t1 = csub(a, c);
  const float2 t2 = cadd(b, d), t3n = cmul_negi(csub(b, d));   // -i*(b-d)
  a = cadd(t0, t2);
  b = cadd(t1, t3n);
  c = csub(t0, t2);
  d = csub(t1, t3n);
}

// forward 16-pt DFT in registers. Input natural order r[n].
// Output: X16[k] lands in r[SW4(k)], SW4(k) = ((k&3)<<2)|(k>>2).
#define C16 0.92387953251f
#define S16 0.38268343236f
#define RS2 0.70710678119f
__device__ __forceinline__ void dft16(float2 r[16]) {
  dft4(r[0], r[4], r[8],  r[12]);
  dft4(r[1], r[5], r[9],  r[13]);
  dft4(r[2], r[6], r[10], r[14]);
  dft4(r[3], r[7], r[11], r[15]);
  const float2 W1 = make_float2(C16, -S16);
  const float2 W2 = make_float2(RS2, -RS2);
  const float2 W3 = make_float2(S16, -C16);
  const float2 W6 = make_float2(-RS2, -RS2);
  const float2 W9 = make_float2(-C16, S16);
  r[5]  = cmul(r[5],  W1);
  r[9]  = cmul(r[9],  W2);
  r[13] = cmul(r[13], W3);
  r[6]  = cmul(r[6],  W2);
  r[10] = cmul_negi(r[10]);        // W16^4 = -i
  r[14] = cmul(r[14], W6);
  r[7]  = cmul(r[7],  W3);
  r[11] = cmul(r[11], W6);
  r[15] = cmul(r[15], W9);
  dft4(r[0],  r[1],  r[2],  r[3]);
  dft4(r[4],  r[5],  r[6],  r[7]);
  dft4(r[8],  r[9],  r[10], r[11]);
  dft4(r[12], r[13], r[14], r[15]);
}
#define SW4(k) ((((k) & 3) << 2) | ((k) >> 2))

// ---------------------------------------------------------------------------
// Kernel 1: transpose + pack. x (B,T,D) f32 -> xp (B, D/2, T) float2  (unchanged)
// ---------------------------------------------------------------------------
__global__ __launch_bounds__(256) void k_transpose_pack(const float* __restrict__ x,
                                                        float2* __restrict__ xp) {
  __shared__ float tT[64][65];     // [d][t]
  const int b  = blockIdx.z;
  const int t0 = blockIdx.x * 64;
  const int d0 = blockIdx.y * 64;
  const int tid = threadIdx.x;

  const int c4 = tid & 15;
  const int r0 = tid >> 4;
  for (int r = r0; r < 64; r += 16) {
    const float4 v = *(const float4*)&x[((size_t)b * T + (t0 + r)) * D + d0 + 4 * c4];
    tT[4 * c4 + 0][r] = v.x;
    tT[4 * c4 + 1][r] = v.y;
    tT[4 * c4 + 2][r] = v.z;
    tT[4 * c4 + 3][r] = v.w;
  }
  __syncthreads();

  const int tt  = tid & 31;
  const int rp0 = tid >> 5;
  for (int rp = rp0; rp < 32; rp += 8) {
    const float2 a  = *(const float2*)&tT[2 * rp][2 * tt];
    const float2 bb = *(const float2*)&tT[2 * rp + 1][2 * tt];
    const float4 o = make_float4(a.x, bb.x, a.y, bb.y);
    *(float4*)&xp[((size_t)b * (D / 2) + (d0 / 2 + rp)) * T + t0 + 2 * tt] = o;
  }
}

// ---------------------------------------------------------------------------
// Kernel 2: register-resident 16x16x16 forward FFT (2 LDS exchanges), then
// top-7 per real signal with shelf-split waves:
//   waves {0,1} own shelf 0 (even d), waves {2,3} own shelf 1 (odd d).
// Each thread owns 16 bins of ONE shelf as packed u64 keys
// (amp_bits|0x80000000 ## 0xFFFF^k) -> argmax + lowest-k tie-break is a
// single u64 max. Per-wave top-7 barrier-free, then one bitonic-16 sort
// merges the 14 candidates per shelf (10 CE steps vs 42 butterfly steps).
// ---------------------------------------------------------------------------
__global__ __launch_bounds__(256) void k_fft_topk(float2* __restrict__ xp) {
  __shared__ float2 Z[PAD(T - 1) + 1];   // ~35 KB
  __shared__ unsigned long long s_cand[2][2][8];  // [shelf][wave-in-shelf][7]

  const int tid  = threadIdx.x;
  const int lane = tid & 63;
  const int wid  = tid >> 6;
  float2* g = xp + (size_t)blockIdx.x * T;

  float2 r[16];
  // coalesced stride-256 loads straight into registers
  #pragma unroll
  for (int a = 0; a < 16; ++a) r[a] = g[(a << 8) + tid];

  // ---- stage A: DFT over high digit; twiddle W4096^(m*k1); scatter k1-major
  dft16(r);
  {
    float s, c;
    __sincosf(6.283185307179586f / 4096.0f * (float)tid, &s, &c);
    const float2 w = make_float2(c, -s);
    float2 t = make_float2(1.0f, 0.0f);
    Z[PAD(tid)] = r[0];
    #pragma unroll
    for (int k1 = 1; k1 < 16; ++k1) {
      t = cmul(t, w);
      Z[PAD((k1 << 8) + tid)] = cmul(r[SW4(k1)], t);
    }
  }
  __syncthreads();

  // ---- stage B: thread (k1, m1) = (tid>>4, tid&15); DFT over mid digit
  {
    const int m1 = tid & 15;
    const int base = ((tid >> 4) << 8) + m1;
    #pragma unroll
    for (int m2 = 0; m2 < 16; ++m2) r[m2] = Z[PAD(base + (m2 << 4))];
    dft16(r);
    float s, c;
    __sincosf(6.283185307179586f / 256.0f * (float)m1, &s, &c);
    const float2 w = make_float2(c, -s);
    float2 t = make_float2(1.0f, 0.0f);
    Z[PAD(base)] = r[0];                 // read-set == write-set: no barrier
    #pragma unroll
    for (int p = 1; p < 16; ++p) {
      t = cmul(t, w);
      Z[PAD(base + (p << 4))] = cmul(r[SW4(p)], t);
    }
  }
  __syncthreads();

  // ---- stage C: thread (k1, p); DFT over low digit; X[256q+16p+k1] -> e=base+q
  {
    const int base = tid << 4;
    #pragma unroll
    for (int m1 = 0; m1 < 16; ++m1) r[m1] = Z[PAD(base + m1)];
    dft16(r);
    #pragma unroll
    for (int q = 0; q < 16; ++q) Z[PAD(base + q)] = r[SW4(q)];
  }
  __syncthreads();

  // ---- shelf-split amplitudes as packed u64 keys; bins k = 1 + u + 128j.
  // amp computed WITHOUT the 0.5 factors (uniform exact x4 scaling preserves
  // the total order and equalities).
  const int sh = wid >> 1;                     // 0: waves 0,1 ; 1: waves 2,3
  const int u  = ((wid & 1) << 6) | lane;      // 0..127 within shelf
  unsigned long long key[16];
  #pragma unroll
  for (int j = 0; j < 16; ++j) {
    const int k = 1 + u + (j << 7);
    if (k >= T / 2) { key[j] = 0ull; continue; }
    const float2 zk = Z[PAD(drev(k))];
    const float2 zn = Z[PAD(drev(T - k))];
    float re, im;
    if (sh == 0) { re = zk.x + zn.x; im = zk.y - zn.y; }
    else         { re = zk.y + zn.y; im = zn.x - zk.x; }
    const float a = re * re + im * im;         // >= 0
    key[j] = ((unsigned long long)(__float_as_uint(a) | 0x80000000u) << 32)
           | (unsigned)(0xFFFFu ^ k);          // smaller k -> larger key on ties
  }

  // ---- per-wave top-7 (no barriers): local u64 max, 6-step butterfly,
  // owner clears winning bin (keys unique), lane 0 records.
  #pragma unroll
  for (int it = 0; it < TOPK; ++it) {
    unsigned long long m = key[0];
    #pragma unroll
    for (int j = 1; j < 16; ++j) m = (key[j] > m) ? key[j] : m;
    #pragma unroll
    for (int off = 1; off < 64; off <<= 1) {
      const unsigned long long o = shfl_xor_u64(m, off);
      m = (o > m) ? o : m;
    }
    #pragma unroll
    for (int j = 0; j < 16; ++j)
      if (key[j] == m) key[j] = 0ull;          // keys unique: exactly the owner
    if (lane == 0) s_cand[sh][wid & 1][it] = m;
  }
  __syncthreads();

  // ---- merge: wave 0 -> shelf 0, wave 2 -> shelf 1, concurrently.
  // 14 candidates in lanes 0..15 (pad 0), bitonic sort 16 descending
  // (all exchanges stay within 16-lane groups: j <= 8).
  if ((wid & 1) == 0) {
    const int sh2 = wid >> 1;
    const int w   = (lane >> 3) & 1;
    const int i   = lane & 7;
    unsigned long long kk =
        (lane < 16 && i < TOPK) ? s_cand[sh2][w][i] : 0ull;
    #pragma unroll
    for (int ksz = 2; ksz <= 16; ksz <<= 1) {
      #pragma unroll
      for (int j = ksz >> 1; j > 0; j >>= 1) {
        const unsigned long long o = shfl_xor_u64(kk, j);
        const bool dirDesc = ((lane & ksz) == 0);
        const bool lower   = ((lane & j) == 0);
        const unsigned long long big = (kk > o) ? kk : o;
        const unsigned long long sml = (kk > o) ? o : kk;
        kk = (lower == dirDesc) ? big : sml;
      }
    }
    if (lane < TOPK) {
      const int k = 0xFFFF ^ (int)(kk & 0xFFFFull);
      const float2 zk = Z[PAD(drev(k))];
      const float2 zn = Z[PAD(drev(T - k))];
      float re, im;
      if (sh2 == 0) { re = 0.5f * (zk.x + zn.x); im = 0.5f * (zk.y - zn.y); }
      else          { re = 0.5f * (zk.y + zn.y); im = 0.5f * (zn.x - zk.x); }
      ((float4*)g)[sh2 * TOPK + lane] = make_float4((float)k, re, im, 0.0f);
    }
  }
}

// ---------------------------------------------------------------------------
// Kernel 3: direct sparse reconstruction, 64t x 64d tile per block (unchanged)
// ---------------------------------------------------------------------------
__global__ __launch_bounds__(256) void k_eval(const float* __restrict__ ws,
                                              float* __restrict__ out) {
  __shared__ float  tile[64][64];
  __shared__ float4 s_coef[64 * TOPK];

  const int tid = threadIdx.x;
  const int b   = blockIdx.z;
  const int d0  = blockIdx.y * 64;
  const int t0  = blockIdx.x * 64;

  for (int idx = tid; idx < 64 * TOPK; idx += 256) {
    const int s = idx / TOPK, j = idx - s * TOPK;
    const int P = (b * D + d0) / 2 + (s >> 1);
    const int sh = s & 1;
    s_coef[idx] = ((const float4*)(ws + (size_t)P * (2 * T)))[sh * TOPK + j];
  }
  __syncthreads();

  const int dl = tid & 63;
  const int tg = tid >> 6;
  const float w0 = 6.283185307179586f / 4096.0f;

  float re[TOPK], im[TOPK], cc[TOPK], ss[TOPK], cd[TOPK], sd[TOPK];
  const int ts = t0 + tg;
  #pragma unroll
  for (int j = 0; j < TOPK; ++j) {
    const float4 v = s_coef[dl * TOPK + j];
    const int k = (int)v.x;
    re[j] = 2.0f * v.y;
    im[j] = 2.0f * v.z;
    const float a0 = w0 * (float)((k * ts) & (T - 1));
    const float ad = w0 * (float)((4 * k) & (T - 1));
    ss[j] = __sinf(a0); cc[j] = __cosf(a0);
    sd[j] = __sinf(ad); cd[j] = __cosf(ad);
  }

  #pragma unroll
  for (int i = 0; i < 16; ++i) {
    float acc = 0.0f;
    #pragma unroll
    for (int j = 0; j < TOPK; ++j) {
      acc += re[j] * cc[j] - im[j] * ss[j];
      const float nc = cc[j] * cd[j] - ss[j] * sd[j];
      const float ns = ss[j] * cd[j] + cc[j] * sd[j];
      cc[j] = nc; ss[j] = ns;
    }
    tile[tg + 4 * i][dl] = acc;
  }
  __syncthreads();

  const int c4 = tid & 15;
  const int rw = tid >> 4;
  for (int rr = rw; rr < 64; rr += 16) {
    const float4 v = *(const float4*)&tile[rr][4 * c4];
    *(float4*)&out[((size_t)b * T + (t0 + rr)) * D + d0 + 4 * c4] = v;
  }
}

// ---------------------------------------------------------------------------
extern "C" void kernel_launch(void* const* d_in, const int* in_sizes, int n_in,
                              void* d_out, int out_size, void* d_ws, size_t ws_size,
                              hipStream_t stream) {
  const float* x = (const float*)d_in[0];
  float* out = (float*)d_out;
  float2* xp = (float2*)d_ws;

  dim3 tgrid(T / 64, D / 64, B);
  hipLaunchKernelGGL(k_transpose_pack, tgrid, dim3(256), 0, stream, x, xp);
  hipLaunchKernelGGL(k_fft_topk, dim3(NPAIR), dim3(256), 0, stream, xp);
  hipLaunchKernelGGL(k_eval, tgrid, dim3(256), 0, stream, (const float*)d_ws, out);
}

// Round 4
// 173.111 us; speedup vs baseline: 1.1441x; 1.0148x over previous
//
#include <hip/hip_runtime.h>
#include <math.h>

#define B 8
#define T 4096
#define D 512
#define NPAIR ((B * D) / 2)   // 2048 signal pairs
#define TOPK 7                // int(log(2047)) = 7
// PAD2 padding function (layout identical to round 3). All hot-path address
// computations are strength-reduced to affine base + compile-time offset;
// the PAD macro itself is only used for Z sizing and the rare generic cases.
#define PAD(e) ((e) + ((e) >> 4) + ((e) >> 8))

// base-16 digit reverse of a 12-bit index (3 hex digits)
__device__ __forceinline__ int drev(int k) {
  return ((k & 15) << 8) | (k & 240) | (k >> 8);
}
// PAD(drev(k)) generic helper (used only for 4 bases + merge-phase reads)
__device__ __forceinline__ int pdrev(int k) {
  const int e = drev(k);
  return PAD(e);
}

__device__ __forceinline__ float2 cmul(float2 a, float2 b) {
  return make_float2(a.x * b.x - a.y * b.y, a.x * b.y + a.y * b.x);
}
__device__ __forceinline__ float2 cadd(float2 a, float2 b) { return make_float2(a.x + b.x, a.y + b.y); }
__device__ __forceinline__ float2 csub(float2 a, float2 b) { return make_float2(a.x - b.x, a.y - b.y); }
__device__ __forceinline__ float2 cmul_negi(float2 a) { return make_float2(a.y, -a.x); }  // a * (-i)

__device__ __forceinline__ unsigned long long shfl_xor_u64(unsigned long long v, int off) {
  const unsigned lo = __shfl_xor((unsigned)v, off);
  const unsigned hi = __shfl_xor((unsigned)(v >> 32), off);
  return ((unsigned long long)hi << 32) | lo;
}
__device__ __forceinline__ unsigned long long umax64(unsigned long long a, unsigned long long b) {
  return (a > b) ? a : b;
}

// forward 4-pt DFT, natural order, in place
__device__ __forceinline__ void dft4(float2& a, float2& b, float2& c, float2& d) {
  const float2 t0 = cadd(a, c), t1 = csub(a, c);
  const float2 t2 = cadd(b, d), t3n = cmul_negi(csub(b, d));   // -i*(b-d)
  a = cadd(t0, t2);
  b = cadd(t1, t3n);
  c = csub(t0, t2);
  d = csub(t1, t3n);
}

// forward 16-pt DFT in registers. Input natural order r[n].
// Output: X16[k] lands in r[SW4(k)], SW4(k) = ((k&3)<<2)|(k>>2).
#define C16 0.92387953251f
#define S16 0.38268343236f
#define RS2 0.70710678119f
__device__ __forceinline__ void dft16(float2 r[16]) {
  dft4(r[0], r[4], r[8],  r[12]);
  dft4(r[1], r[5], r[9],  r[13]);
  dft4(r[2], r[6], r[10], r[14]);
  dft4(r[3], r[7], r[11], r[15]);
  const float2 W1 = make_float2(C16, -S16);
  const float2 W2 = make_float2(RS2, -RS2);
  const float2 W3 = make_float2(S16, -C16);
  const float2 W6 = make_float2(-RS2, -RS2);
  const float2 W9 = make_float2(-C16, S16);
  r[5]  = cmul(r[5],  W1);
  r[9]  = cmul(r[9],  W2);
  r[13] = cmul(r[13], W3);
  r[6]  = cmul(r[6],  W2);
  r[10] = cmul_negi(r[10]);        // W16^4 = -i
  r[14] = cmul(r[14], W6);
  r[7]  = cmul(r[7],  W3);
  r[11] = cmul(r[11], W6);
  r[15] = cmul(r[15], W9);
  dft4(r[0],  r[1],  r[2],  r[3]);
  dft4(r[4],  r[5],  r[6],  r[7]);
  dft4(r[8],  r[9],  r[10], r[11]);
  dft4(r[12], r[13], r[14], r[15]);
}
#define SW4(k) ((((k) & 3) << 2) | ((k) >> 2))

// twiddle power tree: tw[k] = w^k, k=1..15, dependency depth 4 (vs 15 chain)
__device__ __forceinline__ void twiddle_tree(float2 w, float2 tw[16]) {
  tw[1] = w;
  tw[2] = cmul(w, w);
  tw[3] = cmul(tw[1], tw[2]);
  tw[4] = cmul(tw[2], tw[2]);
  tw[5] = cmul(tw[1], tw[4]);
  tw[6] = cmul(tw[2], tw[4]);
  tw[7] = cmul(tw[3], tw[4]);
  tw[8] = cmul(tw[4], tw[4]);
  tw[9]  = cmul(tw[1], tw[8]);
  tw[10] = cmul(tw[2], tw[8]);
  tw[11] = cmul(tw[3], tw[8]);
  tw[12] = cmul(tw[4], tw[8]);
  tw[13] = cmul(tw[5], tw[8]);
  tw[14] = cmul(tw[6], tw[8]);
  tw[15] = cmul(tw[7], tw[8]);
}

// ---------------------------------------------------------------------------
// Kernel 1: transpose + pack. x (B,T,D) f32 -> xp (B, D/2, T) float2  (unchanged)
// ---------------------------------------------------------------------------
__global__ __launch_bounds__(256) void k_transpose_pack(const float* __restrict__ x,
                                                        float2* __restrict__ xp) {
  __shared__ float tT[64][65];     // [d][t]
  const int b  = blockIdx.z;
  const int t0 = blockIdx.x * 64;
  const int d0 = blockIdx.y * 64;
  const int tid = threadIdx.x;

  const int c4 = tid & 15;
  const int r0 = tid >> 4;
  for (int r = r0; r < 64; r += 16) {
    const float4 v = *(const float4*)&x[((size_t)b * T + (t0 + r)) * D + d0 + 4 * c4];
    tT[4 * c4 + 0][r] = v.x;
    tT[4 * c4 + 1][r] = v.y;
    tT[4 * c4 + 2][r] = v.z;
    tT[4 * c4 + 3][r] = v.w;
  }
  __syncthreads();

  const int tt  = tid & 31;
  const int rp0 = tid >> 5;
  for (int rp = rp0; rp < 32; rp += 8) {
    const float2 a  = *(const float2*)&tT[2 * rp][2 * tt];
    const float2 bb = *(const float2*)&tT[2 * rp + 1][2 * tt];
    const float4 o = make_float4(a.x, bb.x, a.y, bb.y);
    *(float4*)&xp[((size_t)b * (D / 2) + (d0 / 2 + rp)) * T + t0 + 2 * tt] = o;
  }
}

// ---------------------------------------------------------------------------
// Kernel 2: register-resident 16x16x16 forward FFT (2 LDS exchanges), then
// shelf-split top-7 (round-3 structure). This round: all LDS addressing
// strength-reduced to per-thread affine bases + compile-time immediates
// (physical addresses IDENTICAL to round 3 — verified affine-exactness of
// PAD over each access family, incl. the drev-gather sequences).
// ---------------------------------------------------------------------------
__global__ __launch_bounds__(256) void k_fft_topk(float2* __restrict__ xp) {
  __shared__ float2 Z[PAD(T - 1) + 1];   // ~35 KB
  __shared__ unsigned long long s_cand[2][2][8];  // [shelf][wave-in-shelf][7]

  const int tid  = threadIdx.x;
  const int lane = tid & 63;
  const int wid  = tid >> 6;
  float2* g = xp + (size_t)blockIdx.x * T;

  float2 r[16];
  // coalesced loads, issued in dft4-consumption order (0,4,8,12 | 1,5,9,13 | ...)
  #pragma unroll
  for (int g4 = 0; g4 < 4; ++g4) {
    #pragma unroll
    for (int a = 0; a < 4; ++a) {
      const int idx = g4 + 4 * a;
      r[idx] = g[(idx << 8) + tid];
    }
  }

  // ---- stage A: DFT over high digit; twiddle W4096^(tid*k1); scatter k1-major
  // PAD(256*k1 + tid) = (tid + (tid>>4)) + 273*k1   [exact, no carries]
  dft16(r);
  {
    float s, c;
    __sincosf(6.283185307179586f / 4096.0f * (float)tid, &s, &c);
    float2 tw[16];
    twiddle_tree(make_float2(c, -s), tw);
    const int pa = tid + (tid >> 4);
    Z[pa] = r[0];
    #pragma unroll
    for (int k1 = 1; k1 < 16; ++k1) Z[pa + 273 * k1] = cmul(r[SW4(k1)], tw[k1]);
  }
  __syncthreads();

  // ---- stage B: thread (k1, m1) = (tid>>4, tid&15); DFT over mid digit
  // PAD(256*k1 + m1 + 16*m2) = (273*k1 + m1) + 17*m2   [exact]
  {
    const int m1  = tid & 15;
    const int pb  = 273 * (tid >> 4) + m1;
    #pragma unroll
    for (int m2 = 0; m2 < 16; ++m2) r[m2] = Z[pb + 17 * m2];
    dft16(r);
    float s, c;
    __sincosf(6.283185307179586f / 256.0f * (float)m1, &s, &c);
    float2 tw[16];
    twiddle_tree(make_float2(c, -s), tw);
    Z[pb] = r[0];                 // read-set == write-set: no barrier
    #pragma unroll
    for (int p = 1; p < 16; ++p) Z[pb + 17 * p] = cmul(r[SW4(p)], tw[p]);
  }
  __syncthreads();

  // ---- stage C: DFT over low digit; X[256q+16p+k1] at elem 16*tid+q
  // PAD(16*tid + q) = (17*tid + (tid>>4)) + q   [exact]
  {
    const int pc = 17 * tid + (tid >> 4);
    #pragma unroll
    for (int m1 = 0; m1 < 16; ++m1) r[m1] = Z[pc + m1];
    dft16(r);
    #pragma unroll
    for (int q = 0; q < 16; ++q) Z[pc + q] = r[SW4(q)];
  }
  __syncthreads();

  // ---- shelf-split amplitudes as packed u64 keys; bins k = 1 + u + 128j.
  // PAD(drev(1+u+128j)) = (j odd ? Bk1 : Bk0) + (j>>1)
  // PAD(drev(4096-(1+u+128j))) = (j odd ? Bn1 : Bn0) - (j>>1)   [derived, exact]
  const int sh = wid >> 1;                     // 0: waves 0,1 ; 1: waves 2,3
  const int u  = ((wid & 1) << 6) | lane;      // 0..127 within shelf
  const int Bk0 = pdrev(1 + u);
  const int Bk1 = pdrev(1 + u + 128);
  const int Bn0 = pdrev(4095 - u);
  const int Bn1 = pdrev(4095 - u - 128);
  unsigned long long key[16];
  #pragma unroll
  for (int j = 0; j < 16; ++j) {
    const int ek = ((j & 1) ? Bk1 : Bk0) + (j >> 1);
    const int en = ((j & 1) ? Bn1 : Bn0) - (j >> 1);
    const float2 zk = Z[ek];
    const float2 zn = Z[en];
    float re, im;
    if (sh == 0) { re = zk.x + zn.x; im = zk.y - zn.y; }
    else         { re = zk.y + zn.y; im = zn.x - zk.x; }
    const float a = re * re + im * im;         // >= 0 (x4-scaled, order-preserving)
    const int k = 1 + u + (j << 7);
    key[j] = ((unsigned long long)(__float_as_uint(a) | 0x80000000u) << 32)
           | (unsigned)(0xFFFFu ^ k);          // smaller k -> larger key on ties
  }
  if (u == 127) key[15] = 0ull;                // the single k==T/2 bin

  // ---- per-wave top-7 (no barriers): two-chain local max, 6-step butterfly,
  // owner clears winning bin (keys unique), lane 0 records.
  #pragma unroll
  for (int it = 0; it < TOPK; ++it) {
    unsigned long long ma = key[0], mb = key[8];
    #pragma unroll
    for (int j = 1; j < 8; ++j) {
      ma = umax64(ma, key[j]);
      mb = umax64(mb, key[8 + j]);
    }
    unsigned long long m = umax64(ma, mb);
    #pragma unroll
    for (int off = 1; off < 64; off <<= 1) {
      const unsigned long long o = shfl_xor_u64(m, off);
      m = umax64(m, o);
    }
    #pragma unroll
    for (int j = 0; j < 16; ++j)
      if (key[j] == m) key[j] = 0ull;          // keys unique: exactly the owner
    if (lane == 0) s_cand[sh][wid & 1][it] = m;
  }
  __syncthreads();

  // ---- merge: wave 0 -> shelf 0, wave 2 -> shelf 1, concurrently.
  // 14 candidates in lanes 0..15 (pad 0), bitonic sort 16 descending.
  if ((wid & 1) == 0) {
    const int sh2 = wid >> 1;
    const int w   = (lane >> 3) & 1;
    const int i   = lane & 7;
    unsigned long long kk =
        (lane < 16 && i < TOPK) ? s_cand[sh2][w][i] : 0ull;
    #pragma unroll
    for (int ksz = 2; ksz <= 16; ksz <<= 1) {
      #pragma unroll
      for (int j = ksz >> 1; j > 0; j >>= 1) {
        const unsigned long long o = shfl_xor_u64(kk, j);
        const bool dirDesc = ((lane & ksz) == 0);
        const bool lower   = ((lane & j) == 0);
        const unsigned long long big = (kk > o) ? kk : o;
        const unsigned long long sml = (kk > o) ? o : kk;
        kk = (lower == dirDesc) ? big : sml;
      }
    }
    if (lane < TOPK) {
      const int k = 0xFFFF ^ (int)(kk & 0xFFFFull);
      const float2 zk = Z[pdrev(k)];
      const float2 zn = Z[pdrev(T - k)];
      float re, im;
      if (sh2 == 0) { re = 0.5f * (zk.x + zn.x); im = 0.5f * (zk.y - zn.y); }
      else          { re = 0.5f * (zk.y + zn.y); im = 0.5f * (zn.x - zk.x); }
      ((float4*)g)[sh2 * TOPK + lane] = make_float4((float)k, re, im, 0.0f);
    }
  }
}

// ---------------------------------------------------------------------------
// Kernel 3: direct sparse reconstruction, 64t x 64d tile per block (unchanged)
// ---------------------------------------------------------------------------
__global__ __launch_bounds__(256) void k_eval(const float* __restrict__ ws,
                                              float* __restrict__ out) {
  __shared__ float  tile[64][64];
  __shared__ float4 s_coef[64 * TOPK];

  const int tid = threadIdx.x;
  const int b   = blockIdx.z;
  const int d0  = blockIdx.y * 64;
  const int t0  = blockIdx.x * 64;

  for (int idx = tid; idx < 64 * TOPK; idx += 256) {
    const int s = idx / TOPK, j = idx - s * TOPK;
    const int P = (b * D + d0) / 2 + (s >> 1);
    const int sh = s & 1;
    s_coef[idx] = ((const float4*)(ws + (size_t)P * (2 * T)))[sh * TOPK + j];
  }
  __syncthreads();

  const int dl = tid & 63;
  const int tg = tid >> 6;
  const float w0 = 6.283185307179586f / 4096.0f;

  float re[TOPK], im[TOPK], cc[TOPK], ss[TOPK], cd[TOPK], sd[TOPK];
  const int ts = t0 + tg;
  #pragma unroll
  for (int j = 0; j < TOPK; ++j) {
    const float4 v = s_coef[dl * TOPK + j];
    const int k = (int)v.x;
    re[j] = 2.0f * v.y;
    im[j] = 2.0f * v.z;
    const float a0 = w0 * (float)((k * ts) & (T - 1));
    const float ad = w0 * (float)((4 * k) & (T - 1));
    ss[j] = __sinf(a0); cc[j] = __cosf(a0);
    sd[j] = __sinf(ad); cd[j] = __cosf(ad);
  }

  #pragma unroll
  for (int i = 0; i < 16; ++i) {
    float acc = 0.0f;
    #pragma unroll
    for (int j = 0; j < TOPK; ++j) {
      acc += re[j] * cc[j] - im[j] * ss[j];
      const float nc = cc[j] * cd[j] - ss[j] * sd[j];
      const float ns = ss[j] * cd[j] + cc[j] * sd[j];
      cc[j] = nc; ss[j] = ns;
    }
    tile[tg + 4 * i][dl] = acc;
  }
  __syncthreads();

  const int c4 = tid & 15;
  const int rw = tid >> 4;
  for (int rr = rw; rr < 64; rr += 16) {
    const float4 v = *(const float4*)&tile[rr][4 * c4];
    *(float4*)&out[((size_t)b * T + (t0 + rr)) * D + d0 + 4 * c4] = v;
  }
}

// ---------------------------------------------------------------------------
extern "C" void kernel_launch(void* const* d_in, const int* in_sizes, int n_in,
                              void* d_out, int out_size, void* d_ws, size_t ws_size,
                              hipStream_t stream) {
  const float* x = (const float*)d_in[0];
  float* out = (float*)d_out;
  float2* xp = (float2*)d_ws;

  dim3 tgrid(T / 64, D / 64, B);
  hipLaunchKernelGGL(k_transpose_pack, tgrid, dim3(256), 0, stream, x, xp);
  hipLaunchKernelGGL(k_fft_topk, dim3(NPAIR), dim3(256), 0, stream, xp);
  hipLaunchKernelGGL(k_eval, tgrid, dim3(256), 0, stream, (const float*)d_ws, out);
}

// Round 6
// 172.860 us; speedup vs baseline: 1.1457x; 1.0015x over previous
//
#include <hip/hip_runtime.h>
#include <math.h>

#define B 8
#define T 4096
#define D 512
#define NPAIR ((B * D) / 2)   // 2048 signal pairs
#define TOPK 7                // int(log(2047)) = 7
// PAD2 padding for the fft kernel's Z (layout identical to rounds 3/4).
#define PAD(e) ((e) + ((e) >> 4) + ((e) >> 8))

// base-16 digit reverse of a 12-bit index (3 hex digits)
__device__ __forceinline__ int drev(int k) {
  return ((k & 15) << 8) | (k & 240) | (k >> 8);
}
// PAD(drev(k)) generic helper (4 bases + merge-phase reads only)
__device__ __forceinline__ int pdrev(int k) {
  const int e = drev(k);
  return PAD(e);
}

__device__ __forceinline__ float2 cmul(float2 a, float2 b) {
  return make_float2(a.x * b.x - a.y * b.y, a.x * b.y + a.y * b.x);
}
__device__ __forceinline__ float2 cadd(float2 a, float2 b) { return make_float2(a.x + b.x, a.y + b.y); }
__device__ __forceinline__ float2 csub(float2 a, float2 b) { return make_float2(a.x - b.x, a.y - b.y); }
__device__ __forceinline__ float2 cmul_negi(float2 a) { return make_float2(a.y, -a.x); }  // a * (-i)

__device__ __forceinline__ unsigned long long shfl_xor_u64(unsigned long long v, int off) {
  const unsigned lo = __shfl_xor((unsigned)v, off);
  const unsigned hi = __shfl_xor((unsigned)(v >> 32), off);
  return ((unsigned long long)hi << 32) | lo;
}
__device__ __forceinline__ unsigned long long umax64(unsigned long long a, unsigned long long b) {
  return (a > b) ? a : b;
}

// forward 4-pt DFT, natural order, in place
__device__ __forceinline__ void dft4(float2& a, float2& b, float2& c, float2& d) {
  const float2 t0 = cadd(a, c), t1 = csub(a, c);
  const float2 t2 = cadd(b, d), t3n = cmul_negi(csub(b, d));   // -i*(b-d)
  a = cadd(t0, t2);
  b = cadd(t1, t3n);
  c = csub(t0, t2);
  d = csub(t1, t3n);
}

// forward 16-pt DFT in registers. Input natural order r[n].
// Output: X16[k] lands in r[SW4(k)], SW4(k) = ((k&3)<<2)|(k>>2).
#define C16 0.92387953251f
#define S16 0.38268343236f
#define RS2 0.70710678119f
__device__ __forceinline__ void dft16(float2 r[16]) {
  dft4(r[0], r[4], r[8],  r[12]);
  dft4(r[1], r[5], r[9],  r[13]);
  dft4(r[2], r[6], r[10], r[14]);
  dft4(r[3], r[7], r[11], r[15]);
  const float2 W1 = make_float2(C16, -S16);
  const float2 W2 = make_float2(RS2, -RS2);
  const float2 W3 = make_float2(S16, -C16);
  const float2 W6 = make_float2(-RS2, -RS2);
  const float2 W9 = make_float2(-C16, S16);
  r[5]  = cmul(r[5],  W1);
  r[9]  = cmul(r[9],  W2);
  r[13] = cmul(r[13], W3);
  r[6]  = cmul(r[6],  W2);
  r[10] = cmul_negi(r[10]);        // W16^4 = -i
  r[14] = cmul(r[14], W6);
  r[7]  = cmul(r[7],  W3);
  r[11] = cmul(r[11], W6);
  r[15] = cmul(r[15], W9);
  dft4(r[0],  r[1],  r[2],  r[3]);
  dft4(r[4],  r[5],  r[6],  r[7]);
  dft4(r[8],  r[9],  r[10], r[11]);
  dft4(r[12], r[13], r[14], r[15]);
}
#define SW4(k) ((((k) & 3) << 2) | ((k) >> 2))

// twiddle power tree: tw[k] = w^k, k=1..15, dependency depth 4
__device__ __forceinline__ void twiddle_tree(float2 w, float2 tw[16]) {
  tw[1] = w;
  tw[2] = cmul(w, w);
  tw[3] = cmul(tw[1], tw[2]);
  tw[4] = cmul(tw[2], tw[2]);
  tw[5] = cmul(tw[1], tw[4]);
  tw[6] = cmul(tw[2], tw[4]);
  tw[7] = cmul(tw[3], tw[4]);
  tw[8] = cmul(tw[4], tw[4]);
  tw[9]  = cmul(tw[1], tw[8]);
  tw[10] = cmul(tw[2], tw[8]);
  tw[11] = cmul(tw[3], tw[8]);
  tw[12] = cmul(tw[4], tw[8]);
  tw[13] = cmul(tw[5], tw[8]);
  tw[14] = cmul(tw[6], tw[8]);
  tw[15] = cmul(tw[7], tw[8]);
}

// ---------------------------------------------------------------------------
// Kernel 1: transpose + pack + FFT STAGE A (fused).
// Block: (mt, dt, b) covers m = mt*16+mi (16 m's), pairs p = dt*16+0..15.
// Gathers the 16 samples t = 256a + m per (pair, m), runs the old stage A
// (dft16 over a, twiddle W4096^(m*k1)) and stores to xp[pair][k1*256 + m]
// -- bit-identical values/layout to the old stage-A output, so k_fft_topk
// picks up at stage B with its global loads replacing the first exchange.
// BW-bound kernel: stage-A VALU (~400 inst/thread, ~2.7 us aggregate) hides
// under its ~20 us traffic floor.
// ---------------------------------------------------------------------------
__global__ __launch_bounds__(256) void k_fftA(const float* __restrict__ x,
                                              float2* __restrict__ xp) {
  // phase1: float tile[256 rows][32 d] (32 KB); phase2: padded [k1][p][mi]
  // pe = e + (e>>4), e = k1*256 + p*16 + mi  ->  pe = 272*k1 + 17*p + mi  (exact)
  __shared__ float2 S[4368];   // 34.9 KB, max(phase1 4096, phase2 4351)

  const int tid = threadIdx.x;
  const int mt  = blockIdx.x;          // m-tile (16 m's)
  const int dt  = blockIdx.y;          // d-tile (32 d's = 16 pairs)
  const int b   = blockIdx.z;

  // ---- phase 1: load 256 rows (t = mt*16 + mi + 256a) x 32 floats
  {
    float* tile = (float*)S;           // tile[r][0..31], r = a*16 + mi
    const int l  = tid & 7;            // float4 slot within row
    const int rb = tid >> 3;           // 0..31
    #pragma unroll
    for (int pass = 0; pass < 8; ++pass) {
      const int r = rb + (pass << 5);
      const int a = r >> 4, mi = r & 15;
      const int t = (mt << 4) + mi + (a << 8);
      const float4 v = *(const float4*)&x[((size_t)b * T + t) * D + (dt << 5) + (l << 2)];
      *(float4*)&tile[(r << 5) + (l << 2)] = v;   // consecutive 16B granules: conflict-free
    }
  }
  __syncthreads();

  // ---- phase 2: thread (p = tid&15, mi = tid>>4): gather a-column, stage A
  float2 r[16];
  const int p  = tid & 15;
  const int mi = tid >> 4;
  #pragma unroll
  for (int a = 0; a < 16; ++a)
    r[a] = S[((a << 4) + mi) * 16 + p];          // pair-bank = p: 4 lanes/pair, free
  __syncthreads();                               // tile fully consumed; S reusable
  dft16(r);
  {
    const int m = (mt << 4) + mi;
    float s, c;
    __sincosf(6.283185307179586f / 4096.0f * (float)m, &s, &c);
    float2 tw[16];
    twiddle_tree(make_float2(c, -s), tw);
    const int pe = 17 * p + mi;                  // + 272*k1
    S[pe] = r[0];
    #pragma unroll
    for (int k1 = 1; k1 < 16; ++k1) S[pe + 272 * k1] = cmul(r[SW4(k1)], tw[k1]);
  }
  __syncthreads();

  // ---- phase 3: coalesced store xp[pair][k1*256 + m], thread (sp, sm)
  {
    const int sp = tid >> 4;                     // pair-in-tile 0..15
    const int sm = tid & 15;                     // mi 0..15
    float2* gp = xp + ((size_t)b * (D / 2) + (dt << 4) + sp) * T + (mt << 4) + sm;
    const int rbase = 17 * sp + sm;              // bank-pair (sp+sm)&15: free
    #pragma unroll
    for (int k1 = 0; k1 < 16; ++k1)
      gp[k1 << 8] = S[rbase + 272 * k1];
  }
}

// ---------------------------------------------------------------------------
// Kernel 2: FFT stages B+C (1 LDS exchange, 3 barriers) + shelf-split top-7.
// Stage-B inputs come straight from global (the old stage-B gather indices,
// 128B-coalesced). All Z addressing byte-identical to round 4.
// ---------------------------------------------------------------------------
__global__ __launch_bounds__(256) void k_fft_topk(float2* __restrict__ xp) {
  __shared__ float2 Z[PAD(T - 1) + 1];   // ~35 KB
  __shared__ unsigned long long s_cand[2][2][8];  // [shelf][wave-in-shelf][7]

  const int tid  = threadIdx.x;
  const int lane = tid & 63;
  const int wid  = tid >> 6;
  float2* g = xp + (size_t)blockIdx.x * T;

  // ---- stage B: thread (k1, m1) = (tid>>4, tid&15); DFT over mid digit.
  // loads element k1*256 + m1 + 16*m2 (== old Z[pb + 17*m2]) from global.
  float2 r[16];
  const int k1 = tid >> 4;
  const int m1 = tid & 15;
  {
    const float2* gsrc = g + (k1 << 8) + m1;
    #pragma unroll
    for (int m2 = 0; m2 < 16; ++m2) r[m2] = gsrc[m2 << 4];
  }
  dft16(r);
  {
    float s, c;
    __sincosf(6.283185307179586f / 256.0f * (float)m1, &s, &c);
    float2 tw[16];
    twiddle_tree(make_float2(c, -s), tw);
    const int pb = 273 * k1 + m1;        // PAD2(256*k1 + m1) ; +17*p steps
    Z[pb] = r[0];
    #pragma unroll
    for (int pp = 1; pp < 16; ++pp) Z[pb + 17 * pp] = cmul(r[SW4(pp)], tw[pp]);
  }
  __syncthreads();

  // ---- stage C: DFT over low digit; PAD2(16*tid + q) = 17*tid + (tid>>4) + q
  {
    const int pc = 17 * tid + (tid >> 4);
    #pragma unroll
    for (int mm = 0; mm < 16; ++mm) r[mm] = Z[pc + mm];
    dft16(r);
    #pragma unroll
    for (int q = 0; q < 16; ++q) Z[pc + q] = r[SW4(q)];
  }
  __syncthreads();

  // ---- shelf-split amplitudes as packed u64 keys; bins k = 1 + u + 128j.
  // PAD2(drev(1+u+128j)) = (j odd ? Bk1 : Bk0) + (j>>1); conjugate side -(j>>1).
  const int sh = wid >> 1;                     // 0: waves 0,1 ; 1: waves 2,3
  const int u  = ((wid & 1) << 6) | lane;      // 0..127 within shelf
  const int Bk0 = pdrev(1 + u);
  const int Bk1 = pdrev(1 + u + 128);
  const int Bn0 = pdrev(4095 - u);
  const int Bn1 = pdrev(4095 - u - 128);
  unsigned long long key[16];
  #pragma unroll
  for (int j = 0; j < 16; ++j) {
    const int ek = ((j & 1) ? Bk1 : Bk0) + (j >> 1);
    const int en = ((j & 1) ? Bn1 : Bn0) - (j >> 1);
    const float2 zk = Z[ek];
    const float2 zn = Z[en];
    float re, im;
    if (sh == 0) { re = zk.x + zn.x; im = zk.y - zn.y; }
    else         { re = zk.y + zn.y; im = zn.x - zk.x; }
    const float a = re * re + im * im;         // >= 0 (x4-scaled, order-preserving)
    const int k = 1 + u + (j << 7);
    key[j] = ((unsigned long long)(__float_as_uint(a) | 0x80000000u) << 32)
           | (unsigned)(0xFFFFu ^ k);          // smaller k -> larger key on ties
  }
  if (u == 127) key[15] = 0ull;                // the single k==T/2 bin

  // ---- per-wave top-7 (no barriers)
  #pragma unroll
  for (int it = 0; it < TOPK; ++it) {
    unsigned long long ma = key[0], mb = key[8];
    #pragma unroll
    for (int j = 1; j < 8; ++j) {
      ma = umax64(ma, key[j]);
      mb = umax64(mb, key[8 + j]);
    }
    unsigned long long m = umax64(ma, mb);
    #pragma unroll
    for (int off = 1; off < 64; off <<= 1) {
      const unsigned long long o = shfl_xor_u64(m, off);
      m = umax64(m, o);
    }
    #pragma unroll
    for (int j = 0; j < 16; ++j)
      if (key[j] == m) key[j] = 0ull;          // keys unique: exactly the owner
    if (lane == 0) s_cand[sh][wid & 1][it] = m;
  }
  __syncthreads();

  // ---- merge: wave 0 -> shelf 0, wave 2 -> shelf 1; bitonic-16 descending
  if ((wid & 1) == 0) {
    const int sh2 = wid >> 1;
    const int w   = (lane >> 3) & 1;
    const int i   = lane & 7;
    unsigned long long kk =
        (lane < 16 && i < TOPK) ? s_cand[sh2][w][i] : 0ull;
    #pragma unroll
    for (int ksz = 2; ksz <= 16; ksz <<= 1) {
      #pragma unroll
      for (int j = ksz >> 1; j > 0; j >>= 1) {
        const unsigned long long o = shfl_xor_u64(kk, j);
        const bool dirDesc = ((lane & ksz) == 0);
        const bool lower   = ((lane & j) == 0);
        const unsigned long long big = (kk > o) ? kk : o;
        const unsigned long long sml = (kk > o) ? o : kk;
        kk = (lower == dirDesc) ? big : sml;
      }
    }
    if (lane < TOPK) {
      const int k = 0xFFFF ^ (int)(kk & 0xFFFFull);
      const float2 zk = Z[pdrev(k)];
      const float2 zn = Z[pdrev(T - k)];
      float re, im;
      if (sh2 == 0) { re = 0.5f * (zk.x + zn.x); im = 0.5f * (zk.y - zn.y); }
      else          { re = 0.5f * (zk.y + zn.y); im = 0.5f * (zn.x - zk.x); }
      ((float4*)g)[sh2 * TOPK + lane] = make_float4((float)k, re, im, 0.0f);
    }
  }
}

// ---------------------------------------------------------------------------
// Kernel 3: direct sparse reconstruction, 64t x 64d tile per block (unchanged)
// ---------------------------------------------------------------------------
__global__ __launch_bounds__(256) void k_eval(const float* __restrict__ ws,
                                              float* __restrict__ out) {
  __shared__ float  tile[64][64];
  __shared__ float4 s_coef[64 * TOPK];

  const int tid = threadIdx.x;
  const int b   = blockIdx.z;
  const int d0  = blockIdx.y * 64;
  const int t0  = blockIdx.x * 64;

  for (int idx = tid; idx < 64 * TOPK; idx += 256) {
    const int s = idx / TOPK, j = idx - s * TOPK;
    const int P = (b * D + d0) / 2 + (s >> 1);
    const int sh = s & 1;
    s_coef[idx] = ((const float4*)(ws + (size_t)P * (2 * T)))[sh * TOPK + j];
  }
  __syncthreads();

  const int dl = tid & 63;
  const int tg = tid >> 6;
  const float w0 = 6.283185307179586f / 4096.0f;

  float re[TOPK], im[TOPK], cc[TOPK], ss[TOPK], cd[TOPK], sd[TOPK];
  const int ts = t0 + tg;
  #pragma unroll
  for (int j = 0; j < TOPK; ++j) {
    const float4 v = s_coef[dl * TOPK + j];
    const int k = (int)v.x;
    re[j] = 2.0f * v.y;
    im[j] = 2.0f * v.z;
    const float a0 = w0 * (float)((k * ts) & (T - 1));
    const float ad = w0 * (float)((4 * k) & (T - 1));
    ss[j] = __sinf(a0); cc[j] = __cosf(a0);
    sd[j] = __sinf(ad); cd[j] = __cosf(ad);
  }

  #pragma unroll
  for (int i = 0; i < 16; ++i) {
    float acc = 0.0f;
    #pragma unroll
    for (int j = 0; j < TOPK; ++j) {
      acc += re[j] * cc[j] - im[j] * ss[j];
      const float nc = cc[j] * cd[j] - ss[j] * sd[j];
      const float ns = ss[j] * cd[j] + cc[j] * sd[j];
      cc[j] = nc; ss[j] = ns;
    }
    tile[tg + 4 * i][dl] = acc;
  }
  __syncthreads();

  const int c4 = tid & 15;
  const int rw = tid >> 4;
  for (int rr = rw; rr < 64; rr += 16) {
    const float4 v = *(const float4*)&tile[rr][4 * c4];
    *(float4*)&out[((size_t)b * T + (t0 + rr)) * D + d0 + 4 * c4] = v;
  }
}

// ---------------------------------------------------------------------------
extern "C" void kernel_launch(void* const* d_in, const int* in_sizes, int n_in,
                              void* d_out, int out_size, void* d_ws, size_t ws_size,
                              hipStream_t stream) {
  const float* x = (const float*)d_in[0];
  float* out = (float*)d_out;
  float2* xp = (float2*)d_ws;

  hipLaunchKernelGGL(k_fftA, dim3(16, 16, B), dim3(256), 0, stream, x, xp);
  hipLaunchKernelGGL(k_fft_topk, dim3(NPAIR), dim3(256), 0, stream, xp);
  hipLaunchKernelGGL(k_eval, dim3(T / 64, D / 64, B), dim3(256), 0, stream,
                     (const float*)d_ws, out);
}